// Round 4
// baseline (258.524 us; speedup 1.0000x reference)
//
#include <hip/hip_runtime.h>

#define HH 64
#define WWID 64
#define CCH 32
#define HFD 96
#define WFD 320
#define NPIX (HFD*WFD)      // 30720
#define NVOX (HH*WWID*CCH)  // 131072

typedef __attribute__((ext_vector_type(8))) short short8;   // 8 bf16 (4 VGPRs)
typedef __attribute__((ext_vector_type(4))) float f32x4;

__device__ __forceinline__ float4 ld4(const float* p){ return *reinterpret_cast<const float4*>(p); }
__device__ __forceinline__ void fma4(float4& a, float s, float4 w){
  a.x = fmaf(s,w.x,a.x); a.y = fmaf(s,w.y,a.y); a.z = fmaf(s,w.z,a.z); a.w = fmaf(s,w.w,a.w);
}
__device__ __forceinline__ void add4(float4& a, float4 w){ a.x+=w.x; a.y+=w.y; a.z+=w.z; a.w+=w.w; }
__device__ __forceinline__ void relu4(float4& a){
  a.x=fmaxf(a.x,0.f); a.y=fmaxf(a.y,0.f); a.z=fmaxf(a.z,0.f); a.w=fmaxf(a.w,0.f);
}
__device__ __forceinline__ unsigned short f2bf(float f){   // RTN-even f32 -> bf16
  unsigned int u = __float_as_uint(f);
  return (unsigned short)((u + 0x7FFFu + ((u>>16)&1u)) >> 16);
}

// ---------------- prep: per (voxel, neighbor) compute pixel index + dist ----------------
__global__ __launch_bounds__(256) void prep_kernel(
    const float* __restrict__ kdtree, const float* __restrict__ Tr,
    const float* __restrict__ R0, const float* __restrict__ P3,
    float4* __restrict__ nb)
{
  int gid = blockIdx.x*256 + threadIdx.x;   // 0 .. NVOX*2-1
  double PR[12], M[12];
  #pragma unroll
  for (int e=0;e<3;e++)
    #pragma unroll
    for (int b=0;b<4;b++){
      double s = 0.0;
      #pragma unroll
      for (int a=0;a<4;a++) s += (double)P3[e*4+a]*(double)R0[a*4+b];
      PR[e*4+b] = s;
    }
  #pragma unroll
  for (int e=0;e<3;e++)
    #pragma unroll
    for (int d=0;d<4;d++){
      double s = 0.0;
      #pragma unroll
      for (int b=0;b<4;b++) s += PR[e*4+b]*(double)Tr[b*4+d];
      M[e*4+d] = s;
    }
  int v = gid>>1, k = gid&1;
  int c = v&31, w = (v>>5)&63, h = v>>11;
  size_t off = ((((size_t)(h*4)*256 + (size_t)(w*4))*32 + c)*2 + k)*4;
  float4 kp = ld4(kdtree + off);
  double k0=kp.x, k1=kp.y, k2=kp.z;
  double cam0 = M[0]*k0 + M[1]*k1 + M[2]*k2 + M[3];
  double cam1 = M[4]*k0 + M[5]*k1 + M[6]*k2 + M[7];
  double cam2 = M[8]*k0 + M[9]*k1 + M[10]*k2 + M[11];
  float zf = (float)cam2;
  double zd = (fabsf(zf) < 1e-6f) ? (double)1e-6f : cam2;
  double py = cam1/zd, px = cam0/zd;
  int ty = (int)py, tx = (int)px;            // trunc toward zero, matches astype(int32)
  int iy = ty < 0 ? 0 : ((ty>>2) > (HFD-1) ? (HFD-1) : (ty>>2));
  int ix = tx < 0 ? 0 : ((tx>>2) > (WFD-1) ? (WFD-1) : (tx>>2));
  float4 r;
  r.x = __int_as_float(iy*WFD + ix);
  r.y = kp.x - 1.0f;
  r.z = kp.y - (float)(h*4);
  r.w = kp.z - (float)(w*4);
  nb[gid] = r;
}

// ---------------- wcvt: build transposed bf16 weight table Wt[n][k], n,k in 0..255 ----------------
// Wt[n][k] = (n<128) ? w1[k][n] : w1[259+k][n-128]
__global__ __launch_bounds__(256) void wcvt_kernel(const float* __restrict__ w1,
                                                   unsigned short* __restrict__ wt)
{
  int e = blockIdx.x*256 + threadIdx.x;      // 0..65535
  int n = e>>8, k = e&255;
  float v = (n<128) ? w1[k*128 + n] : w1[(259+k)*128 + (n-128)];
  wt[n*256 + k] = f2bf(v);
}

// ---------------- pix: bf16 MFMA GEMM, C[30720x256] = X[30720x256] @ W'[256x256] ----------------
// Block: 64 rows x 256 cols, K=256 staged once in LDS (XOR-swizzled). 4 waves split N.
__global__ __launch_bounds__(256) void pix_mfma(
    const float* __restrict__ input, const unsigned short* __restrict__ wt,
    float* __restrict__ pix)
{
  __shared__ unsigned short As[64*256];      // 32 KB, byte ^= (row&7)<<4 swizzle
  int t = threadIdx.x;
  long pbase = (long)blockIdx.x*64;
  const float* src = input + pbase*256;
  // stage: 64x256 f32 -> bf16 LDS
  float4 xv[16];
  #pragma unroll
  for (int i=0;i<16;i++) xv[i] = ld4(src + i*1024 + t*4);
  #pragma unroll
  for (int i=0;i<16;i++){
    int e = i*1024 + t*4;
    int row = e>>8, k = e&255;
    ushort4 u;
    u.x = f2bf(xv[i].x); u.y = f2bf(xv[i].y); u.z = f2bf(xv[i].z); u.w = f2bf(xv[i].w);
    unsigned byteoff = (unsigned)((row*512 + k*2) ^ ((row&7)<<4));
    *reinterpret_cast<ushort4*>(reinterpret_cast<char*>(As) + byteoff) = u;
  }
  __syncthreads();

  int l = t & 63, wv = t >> 6;               // lane, wave
  int rl = l & 15, khi = l >> 4;
  unsigned xorv = (unsigned)((rl & 7) << 4);
  const unsigned short* wb = wt + (size_t)(wv*64 + rl)*256 + khi*8;

  f32x4 acc[4][4];
  #pragma unroll
  for (int m=0;m<4;m++)
    #pragma unroll
    for (int n=0;n<4;n++) acc[m][n] = (f32x4){0.f,0.f,0.f,0.f};

  #pragma unroll
  for (int kk=0; kk<8; ++kk){
    short8 a[4], b[4];
    #pragma unroll
    for (int m=0;m<4;m++){
      int rowA = m*16 + rl;
      int kA   = kk*32 + khi*8;
      unsigned off = (unsigned)((rowA*512 + kA*2) ^ xorv);
      a[m] = *reinterpret_cast<const short8*>(reinterpret_cast<const char*>(As) + off);
    }
    #pragma unroll
    for (int n=0;n<4;n++)
      b[n] = *reinterpret_cast<const short8*>(wb + n*16*256 + kk*32);
    #pragma unroll
    for (int m=0;m<4;m++)
      #pragma unroll
      for (int n=0;n<4;n++)
        acc[m][n] = __builtin_amdgcn_mfma_f32_16x16x32_bf16(a[m], b[n], acc[m][n], 0, 0, 0);
  }

  // epilogue: D col = lane&15, row = (lane>>4)*4 + i  [m89-verified]
  #pragma unroll
  for (int m=0;m<4;m++){
    #pragma unroll
    for (int n=0;n<4;n++){
      int row = m*16 + khi*4;
      int col = wv*64 + n*16 + rl;
      float* o = pix + (pbase + row)*256 + col;
      o[0]   = acc[m][n][0];
      o[256] = acc[m][n][1];
      o[512] = acc[m][n][2];
      o[768] = acc[m][n][3];
    }
  }
}

// ---------------- vox: assemble h1 (LDS), layer2 register-tiled, layer3 ----------------
__global__ __launch_bounds__(256) void vox_kernel(
    const float4* __restrict__ nb, const float* __restrict__ pix,
    const float* __restrict__ w1, const float* __restrict__ b1,
    const float* __restrict__ w2, const float* __restrict__ b2,
    const float* __restrict__ w3, const float* __restrict__ b3,
    float* __restrict__ mlpout)
{
  __shared__ float sm[64*132];               // h1: 33.8 KB
  __shared__ float sm2[64*68];               // h2: 17.4 KB
  int t = threadIdx.x;
  int vb = blockIdx.x*64;
  // ---- phase A: h1 = gather(pixA)+gather(pixB) + dist@w1_dist + b1, relu -> sm ----
  {
    int r = t>>2, q = t&3;                   // voxel r, col-quarter q (4 lanes/row -> 128B contig)
    int v = vb + r;
    float4 n0 = nb[(size_t)v*2], n1 = nb[(size_t)v*2+1];
    int i0 = __float_as_int(n0.x), i1 = __float_as_int(n1.x);
    const float* q0 = pix + (size_t)i0*256 + q*32;
    const float* q1 = pix + (size_t)i1*256 + 128 + q*32;
    float4 g0[8], g1[8];
    #pragma unroll
    for (int j=0;j<8;j++){ g0[j] = ld4(q0 + j*4); g1[j] = ld4(q1 + j*4); }
    const float* wd = w1 + 256*128 + q*32;   // dist rows k=0: 256..258
    const float* we = w1 + 515*128 + q*32;   // dist rows k=1: 515..517
    const float* bb = b1 + q*32;
    float* dst = sm + r*132 + q*32;
    #pragma unroll
    for (int j=0;j<8;j++){
      float4 h = g0[j];
      add4(h, g1[j]);
      fma4(h, n0.y, ld4(wd + j*4));
      fma4(h, n0.z, ld4(wd + 128 + j*4));
      fma4(h, n0.w, ld4(wd + 256 + j*4));
      fma4(h, n1.y, ld4(we + j*4));
      fma4(h, n1.z, ld4(we + 128 + j*4));
      fma4(h, n1.w, ld4(we + 256 + j*4));
      add4(h, ld4(bb + j*4));
      relu4(h);
      *reinterpret_cast<float4*>(dst + j*4) = h;
    }
  }
  __syncthreads();
  // ---- phase B: layer2 (128->64), thread = 4 voxels x 4 cols ----
  {
    int vg = t>>4, cg = t&15;
    const float* xrow = sm + (vg*4)*132;
    const float* w2c  = w2 + cg*4;
    float4 a2[4];
    #pragma unroll
    for (int p=0;p<4;p++) a2[p] = make_float4(0,0,0,0);
    #pragma unroll 2
    for (int f=0; f<128; ++f){
      float4 wvv = ld4(w2c + (size_t)f*64);
      #pragma unroll
      for (int p=0;p<4;p++)
        fma4(a2[p], xrow[p*132 + f], wvv);
    }
    float4 bv = ld4(b2 + cg*4);
    #pragma unroll
    for (int p=0;p<4;p++){
      add4(a2[p], bv); relu4(a2[p]);
      *reinterpret_cast<float4*>(&sm2[(vg*4+p)*68 + cg*4]) = a2[p];
    }
  }
  __syncthreads();
  // ---- phase C: layer3 (64->1) + reduce over 4 lanes ----
  {
    int r = t>>2, g = t&3;
    const float* h2  = sm2 + r*68 + g*16;
    const float* w3c = w3 + g*16;
    float part = 0.f;
    #pragma unroll
    for (int j=0;j<16;j++) part = fmaf(h2[j], w3c[j], part);
    part += __shfl_xor(part, 1);
    part += __shfl_xor(part, 2);
    if (g == 0) mlpout[vb + r] = part + b3[0];
  }
}

// ---------------- conv: channel scramble + 1x1 conv ----------------
__global__ __launch_bounds__(256) void conv_kernel(
    const float* __restrict__ mlpout, const float* __restrict__ conv_w,
    const float* __restrict__ conv_b, float* __restrict__ y)
{
  int t = blockIdx.x*256 + threadIdx.x;      // 0..4095
  int i = t>>6, j = t&63;
  int c = i>>1;
  int base = ((i&1)<<11) + j*32;
  float acc = conv_b[0];
  #pragma unroll
  for (int k=0;k<32;++k)
    acc = fmaf(conv_w[k], mlpout[(size_t)(base+k)*32 + c], acc);
  y[t] = acc;
}

extern "C" void kernel_launch(void* const* d_in, const int* in_sizes, int n_in,
                              void* d_out, int out_size, void* d_ws, size_t ws_size,
                              hipStream_t stream)
{
  const float* input  = (const float*)d_in[0];
  const float* kdtree = (const float*)d_in[1];
  const float* Tr     = (const float*)d_in[2];
  const float* R0     = (const float*)d_in[3];
  const float* P3     = (const float*)d_in[4];
  const float* w1     = (const float*)d_in[5];
  const float* b1     = (const float*)d_in[6];
  const float* w2     = (const float*)d_in[7];
  const float* b2     = (const float*)d_in[8];
  const float* w3     = (const float*)d_in[9];
  const float* b3     = (const float*)d_in[10];
  const float* conv_w = (const float*)d_in[11];
  const float* conv_b = (const float*)d_in[12];

  float* ws      = (float*)d_ws;
  float* pix     = ws;                                        // NPIX*256 f32 (31.5 MB)
  float4* nb     = (float4*)(ws + (size_t)NPIX*256);          // NVOX*2 float4 (4 MB)
  float* mlpout  = ws + (size_t)NPIX*256 + (size_t)NVOX*8;    // NVOX f32 (0.5 MB)
  unsigned short* wt = (unsigned short*)(ws + (size_t)NPIX*256 + (size_t)NVOX*8 + NVOX); // 128 KB bf16
  float* y       = (float*)d_out;

  hipLaunchKernelGGL(wcvt_kernel, dim3(256),         dim3(256), 0, stream, w1, wt);
  hipLaunchKernelGGL(prep_kernel, dim3(NVOX*2/256),  dim3(256), 0, stream, kdtree, Tr, R0, P3, nb);
  hipLaunchKernelGGL(pix_mfma,    dim3(NPIX/64),     dim3(256), 0, stream, input, wt, pix);
  hipLaunchKernelGGL(vox_kernel,  dim3(NVOX/64),     dim3(256), 0, stream, nb, pix, w1, b1, w2, b2, w3, b3, mlpout);
  hipLaunchKernelGGL(conv_kernel, dim3(16),          dim3(256), 0, stream, mlpout, conv_w, conv_b, y);
}

// Round 6
// 187.426 us; speedup vs baseline: 1.3793x; 1.3793x over previous
//
#include <hip/hip_runtime.h>

#define HH 64
#define WWID 64
#define CCH 32
#define HFD 96
#define WFD 320
#define NPIX (HFD*WFD)      // 30720
#define NVOX (HH*WWID*CCH)  // 131072

typedef __attribute__((ext_vector_type(8))) short short8;   // 8 bf16 (4 VGPRs)
typedef __attribute__((ext_vector_type(4))) float f32x4;

__device__ __forceinline__ float4 ld4(const float* p){ return *reinterpret_cast<const float4*>(p); }
__device__ __forceinline__ unsigned short f2bf(float f){   // RTN-even f32 -> bf16
  unsigned int u = __float_as_uint(f);
  return (unsigned short)((u + 0x7FFFu + ((u>>16)&1u)) >> 16);
}
__device__ __forceinline__ float bf2f(unsigned short s){
  return __uint_as_float(((unsigned int)s) << 16);
}

// ---------------- prep: per (voxel, neighbor) compute pixel index + dist ----------------
__global__ __launch_bounds__(256) void prep_kernel(
    const float* __restrict__ kdtree, const float* __restrict__ Tr,
    const float* __restrict__ R0, const float* __restrict__ P3,
    float4* __restrict__ nb)
{
  int gid = blockIdx.x*256 + threadIdx.x;   // 0 .. NVOX*2-1
  double PR[12], M[12];
  #pragma unroll
  for (int e=0;e<3;e++)
    #pragma unroll
    for (int b=0;b<4;b++){
      double s = 0.0;
      #pragma unroll
      for (int a=0;a<4;a++) s += (double)P3[e*4+a]*(double)R0[a*4+b];
      PR[e*4+b] = s;
    }
  #pragma unroll
  for (int e=0;e<3;e++)
    #pragma unroll
    for (int d=0;d<4;d++){
      double s = 0.0;
      #pragma unroll
      for (int b=0;b<4;b++) s += PR[e*4+b]*(double)Tr[b*4+d];
      M[e*4+d] = s;
    }
  int v = gid>>1, k = gid&1;
  int c = v&31, w = (v>>5)&63, h = v>>11;
  size_t off = ((((size_t)(h*4)*256 + (size_t)(w*4))*32 + c)*2 + k)*4;
  float4 kp = ld4(kdtree + off);
  double k0=kp.x, k1=kp.y, k2=kp.z;
  double cam0 = M[0]*k0 + M[1]*k1 + M[2]*k2 + M[3];
  double cam1 = M[4]*k0 + M[5]*k1 + M[6]*k2 + M[7];
  double cam2 = M[8]*k0 + M[9]*k1 + M[10]*k2 + M[11];
  float zf = (float)cam2;
  double zd = (fabsf(zf) < 1e-6f) ? (double)1e-6f : cam2;
  double py = cam1/zd, px = cam0/zd;
  int ty = (int)py, tx = (int)px;            // trunc toward zero, matches astype(int32)
  int iy = ty < 0 ? 0 : ((ty>>2) > (HFD-1) ? (HFD-1) : (ty>>2));
  int ix = tx < 0 ? 0 : ((tx>>2) > (WFD-1) ? (WFD-1) : (tx>>2));
  float4 r;
  r.x = __int_as_float(iy*WFD + ix);
  r.y = kp.x - 1.0f;
  r.z = kp.y - (float)(h*4);
  r.w = kp.z - (float)(w*4);
  nb[gid] = r;
}

// ---------------- wcvt: bf16 weight tables ----------------
// wt[n][k]  (256x256): n<128 -> w1[k][n] ; n>=128 -> w1[259+k][n-128]   (pix GEMM B)
// w2t[c][k] (64x128):  w2[k][c]                                         (mlp2 B)
__global__ __launch_bounds__(256) void wcvt_kernel(const float* __restrict__ w1,
                                                   const float* __restrict__ w2,
                                                   unsigned short* __restrict__ wt,
                                                   unsigned short* __restrict__ w2t)
{
  int e = blockIdx.x*256 + threadIdx.x;
  if (e < 65536){
    int n = e>>8, k = e&255;
    float v = (n<128) ? w1[k*128 + n] : w1[(259+k)*128 + (n-128)];
    wt[n*256 + k] = f2bf(v);
  } else {
    int e2 = e - 65536;                      // 0..8191
    int c = e2>>7, k = e2&127;
    w2t[c*128 + k] = f2bf(w2[k*64 + c]);
  }
}

// ---------------- pix: bf16 MFMA GEMM, pixb[30720x256](bf16) = X @ W' ----------------
__global__ __launch_bounds__(256) void pix_mfma(
    const float* __restrict__ input, const unsigned short* __restrict__ wt,
    unsigned short* __restrict__ pixb)
{
  __shared__ unsigned short sm[64*264];      // staging (first 32KB, swizzled) / epilogue 64x264
  int t = threadIdx.x;
  long pbase = (long)blockIdx.x*64;
  const float* src = input + pbase*256;
  float4 xv[16];
  #pragma unroll
  for (int i=0;i<16;i++) xv[i] = ld4(src + i*1024 + t*4);
  #pragma unroll
  for (int i=0;i<16;i++){
    int e = i*1024 + t*4;
    int row = e>>8, k = e&255;
    ushort4 u;
    u.x = f2bf(xv[i].x); u.y = f2bf(xv[i].y); u.z = f2bf(xv[i].z); u.w = f2bf(xv[i].w);
    unsigned byteoff = (unsigned)((row*512 + k*2) ^ ((row&7)<<4));
    *reinterpret_cast<ushort4*>(reinterpret_cast<char*>(sm) + byteoff) = u;
  }
  __syncthreads();

  int l = t & 63, wv = t >> 6;
  int rl = l & 15, khi = l >> 4;
  unsigned xorv = (unsigned)((rl & 7) << 4);
  const unsigned short* wb = wt + (size_t)(wv*64 + rl)*256 + khi*8;

  f32x4 acc[4][4];
  #pragma unroll
  for (int m=0;m<4;m++)
    #pragma unroll
    for (int n=0;n<4;n++) acc[m][n] = (f32x4){0.f,0.f,0.f,0.f};

  #pragma unroll
  for (int kk=0; kk<8; ++kk){
    short8 a[4], b[4];
    #pragma unroll
    for (int m=0;m<4;m++){
      unsigned off = (unsigned)(((m*16+rl)*512 + (kk*32 + khi*8)*2) ^ xorv);
      a[m] = *reinterpret_cast<const short8*>(reinterpret_cast<const char*>(sm) + off);
    }
    #pragma unroll
    for (int n=0;n<4;n++)
      b[n] = *reinterpret_cast<const short8*>(wb + n*16*256 + kk*32);
    #pragma unroll
    for (int m=0;m<4;m++)
      #pragma unroll
      for (int n=0;n<4;n++)
        acc[m][n] = __builtin_amdgcn_mfma_f32_16x16x32_bf16(a[m], b[n], acc[m][n], 0, 0, 0);
  }

  __syncthreads();                           // all A-frag reads done; reuse sm for transpose
  #pragma unroll
  for (int m=0;m<4;m++)
    #pragma unroll
    for (int n=0;n<4;n++){
      int col = wv*64 + n*16 + rl;
      #pragma unroll
      for (int i=0;i<4;i++){
        int row = m*16 + khi*4 + i;
        sm[row*264 + col] = f2bf(acc[m][n][i]);
      }
    }
  __syncthreads();
  // coalesced bf16 store: thread (r0=t>>4, c16=t&15), 4 rows x 32B
  #pragma unroll
  for (int i=0;i<4;i++){
    int row = (t>>4) + i*16;
    const unsigned short* sp = sm + row*264 + (t&15)*16;
    short8 v0 = *reinterpret_cast<const short8*>(sp);
    short8 v1 = *reinterpret_cast<const short8*>(sp+8);
    unsigned short* dst = pixb + (pbase+row)*256 + (t&15)*16;
    *reinterpret_cast<short8*>(dst)   = v0;
    *reinterpret_cast<short8*>(dst+8) = v1;
  }
}

// ---------------- h1: barrier-free gather + layer-1 tail -> h1b (bf16) ----------------
// thread = (voxel, col-octet): 16 lanes cooperatively read one 256B pix row.
__global__ __launch_bounds__(256) void h1_kernel(
    const float4* __restrict__ nb, const unsigned short* __restrict__ pixb,
    const float* __restrict__ w1, const float* __restrict__ b1,
    unsigned short* __restrict__ h1b)
{
  int gid = blockIdx.x*256 + threadIdx.x;    // 0 .. NVOX*16-1
  int v = gid>>4, o = (gid&15)*8;
  float4 n0 = nb[(size_t)v*2], n1 = nb[(size_t)v*2+1];
  int i0 = __float_as_int(n0.x), i1 = __float_as_int(n1.x);
  short8 pA = *reinterpret_cast<const short8*>(pixb + (size_t)i0*256 + o);
  short8 pB = *reinterpret_cast<const short8*>(pixb + (size_t)i1*256 + 128 + o);
  const float* wd = w1 + 256*128 + o;        // dist rows k=0: 256..258
  const float* we = w1 + 515*128 + o;        // dist rows k=1: 515..517
  union { short8 s; unsigned short u[8]; } pk;
  #pragma unroll
  for (int j=0;j<8;j++){
    float x = bf2f((unsigned short)pA[j]) + bf2f((unsigned short)pB[j]);
    x = fmaf(n0.y, wd[j],     x);
    x = fmaf(n0.z, wd[128+j], x);
    x = fmaf(n0.w, wd[256+j], x);
    x = fmaf(n1.y, we[j],     x);
    x = fmaf(n1.z, we[128+j], x);
    x = fmaf(n1.w, we[256+j], x);
    x += b1[o+j];
    pk.u[j] = f2bf(fmaxf(x, 0.f));
  }
  *reinterpret_cast<short8*>(h1b + (size_t)v*128 + o) = pk.s;
}

// ---------------- mlp2: MFMA layers 2+3 -> mlpout ----------------
// block = 128 voxel rows (4 waves x 32). h2 = relu(h1@w2+b2) in-register, out = h2.w3+b3.
__global__ __launch_bounds__(256) void mlp2_kernel(
    const unsigned short* __restrict__ h1b, const unsigned short* __restrict__ w2t,
    const float* __restrict__ b2, const float* __restrict__ w3,
    const float* __restrict__ b3, float* __restrict__ mlpout)
{
  int t = threadIdx.x;
  int l = t&63, wv = t>>6;
  int rl = l&15, khi = l>>4;
  int rowbase = blockIdx.x*128 + wv*32;

  f32x4 acc[2][4];
  #pragma unroll
  for (int m=0;m<2;m++)
    #pragma unroll
    for (int n=0;n<4;n++) acc[m][n] = (f32x4){0.f,0.f,0.f,0.f};

  #pragma unroll
  for (int kk=0; kk<4; ++kk){
    short8 a[2], b[4];
    #pragma unroll
    for (int m=0;m<2;m++)
      a[m] = *reinterpret_cast<const short8*>(h1b + (size_t)(rowbase + m*16 + rl)*128 + kk*32 + khi*8);
    #pragma unroll
    for (int n=0;n<4;n++)
      b[n] = *reinterpret_cast<const short8*>(w2t + (size_t)(n*16 + rl)*128 + kk*32 + khi*8);
    #pragma unroll
    for (int m=0;m<2;m++)
      #pragma unroll
      for (int n=0;n<4;n++)
        acc[m][n] = __builtin_amdgcn_mfma_f32_16x16x32_bf16(a[m], b[n], acc[m][n], 0, 0, 0);
  }

  float b2v[4], w3v[4];
  #pragma unroll
  for (int n=0;n<4;n++){ b2v[n] = b2[n*16+rl]; w3v[n] = w3[n*16+rl]; }
  float bias3 = b3[0];
  #pragma unroll
  for (int m=0;m<2;m++){
    #pragma unroll
    for (int i=0;i<4;i++){
      float s = 0.f;
      #pragma unroll
      for (int n=0;n<4;n++)
        s = fmaf(fmaxf(acc[m][n][i] + b2v[n], 0.f), w3v[n], s);
      s += __shfl_xor(s, 1);
      s += __shfl_xor(s, 2);
      s += __shfl_xor(s, 4);
      s += __shfl_xor(s, 8);
      if (rl == 0) mlpout[rowbase + m*16 + khi*4 + i] = s + bias3;
    }
  }
}

// ---------------- conv: channel scramble + 1x1 conv ----------------
__global__ __launch_bounds__(256) void conv_kernel(
    const float* __restrict__ mlpout, const float* __restrict__ conv_w,
    const float* __restrict__ conv_b, float* __restrict__ y)
{
  int t = blockIdx.x*256 + threadIdx.x;      // 0..4095
  int i = t>>6, j = t&63;
  int c = i>>1;
  int base = ((i&1)<<11) + j*32;
  float acc = conv_b[0];
  #pragma unroll
  for (int k=0;k<32;++k)
    acc = fmaf(conv_w[k], mlpout[(size_t)(base+k)*32 + c], acc);
  y[t] = acc;
}

extern "C" void kernel_launch(void* const* d_in, const int* in_sizes, int n_in,
                              void* d_out, int out_size, void* d_ws, size_t ws_size,
                              hipStream_t stream)
{
  const float* input  = (const float*)d_in[0];
  const float* kdtree = (const float*)d_in[1];
  const float* Tr     = (const float*)d_in[2];
  const float* R0     = (const float*)d_in[3];
  const float* P3     = (const float*)d_in[4];
  const float* w1     = (const float*)d_in[5];
  const float* b1     = (const float*)d_in[6];
  const float* w2     = (const float*)d_in[7];
  const float* b2     = (const float*)d_in[8];
  const float* w3     = (const float*)d_in[9];
  const float* b3     = (const float*)d_in[10];
  const float* conv_w = (const float*)d_in[11];
  const float* conv_b = (const float*)d_in[12];

  char* wsb = (char*)d_ws;
  unsigned short* pixb = (unsigned short*)wsb;                  // 15,728,640 B
  float4* nb           = (float4*)(wsb + 15728640);             //  4,194,304 B
  unsigned short* h1b  = (unsigned short*)(wsb + 19922944);     // 33,554,432 B
  float* mlpout        = (float*)(wsb + 53477376);              //    524,288 B
  unsigned short* wt   = (unsigned short*)(wsb + 54001664);     //    131,072 B
  unsigned short* w2t  = (unsigned short*)(wsb + 54132736);     //     16,384 B
  float* y = (float*)d_out;

  hipLaunchKernelGGL(wcvt_kernel, dim3(288),        dim3(256), 0, stream, w1, w2, wt, w2t);
  hipLaunchKernelGGL(prep_kernel, dim3(NVOX*2/256), dim3(256), 0, stream, kdtree, Tr, R0, P3, nb);
  hipLaunchKernelGGL(pix_mfma,    dim3(NPIX/64),    dim3(256), 0, stream, input, wt, pixb);
  hipLaunchKernelGGL(h1_kernel,   dim3(NVOX*16/256),dim3(256), 0, stream, nb, pixb, w1, b1, h1b);
  hipLaunchKernelGGL(mlp2_kernel, dim3(NVOX/128),   dim3(256), 0, stream, h1b, w2t, b2, w3, b3, mlpout);
  hipLaunchKernelGGL(conv_kernel, dim3(16),         dim3(256), 0, stream, mlpout, conv_w, conv_b, y);
}